// Round 2
// baseline (10782.487 us; speedup 1.0000x reference)
//
#include <hip/hip_runtime.h>
#include <hip/hip_bf16.h>
#include <type_traits>

typedef __hip_bfloat16 bf16;

#define D_DIM 300
#define TPB 320  // 300 active lanes, padded to 5 waves

__device__ inline float bf_raw2f(unsigned int u) {
  unsigned int x = u << 16;
  float f;
  __builtin_memcpy(&f, &x, 4);
  return f;
}

// ---------------- utility ----------------

__global__ void zero_u32_kernel(unsigned int* __restrict__ p, long long n) {
  long long i = (long long)blockIdx.x * blockDim.x + threadIdx.x;
  long long s = (long long)gridDim.x * blockDim.x;
  for (; i < n; i += s) p[i] = 0u;
}

// ---------------- elementwise / graph kernels ----------------

__global__ void init_h_kernel(const int* __restrict__ atom, const int* __restrict__ chir,
                              const float* __restrict__ e1, const float* __restrict__ e2,
                              float* __restrict__ h) {
  int n = blockIdx.x;
  int d = threadIdx.x;
  if (d >= D_DIM) return;
  int a = atom[n], c = chir[n];
  h[(size_t)n * D_DIM + d] = e1[a * D_DIM + d] + e2[c * D_DIM + d];
}

// ct[l][c][d]: c in 0..11 -> ee1[l][c/3]+ee2[l][c%3]; c==12 -> self-loop const ee1[l][4]+ee2[l][0]
__global__ void combo_kernel(const float* __restrict__ ee1, const float* __restrict__ ee2,
                             float* __restrict__ ct) {
  int l = blockIdx.x / 13, c = blockIdx.x % 13;
  int d = threadIdx.x;
  if (d >= D_DIM) return;
  int bt = (c < 12) ? (c / 3) : 4;
  int bd = (c < 12) ? (c % 3) : 0;
  ct[((size_t)(l * 13 + c)) * D_DIM + d] =
      ee1[(size_t)(l * 5 + bt) * D_DIM + d] + ee2[(size_t)(l * 3 + bd) * D_DIM + d];
}

__global__ void edge_combo_kernel(const int* __restrict__ bt, const int* __restrict__ bd,
                                  int* __restrict__ ec, int E) {
  int e = blockIdx.x * blockDim.x + threadIdx.x;
  if (e < E) ec[e] = bt[e] * 3 + bd[e];
}

__global__ void agg_init_kernel(const float* __restrict__ h, const float* __restrict__ ct_l,
                                float* __restrict__ agg) {
  int n = blockIdx.x;
  int d = threadIdx.x;
  if (d >= D_DIM) return;
  agg[(size_t)n * D_DIM + d] = h[(size_t)n * D_DIM + d] + ct_l[12 * D_DIM + d];
}

__global__ void scatter_kernel(const float* __restrict__ h, const int* __restrict__ row,
                               const int* __restrict__ col, const int* __restrict__ ec,
                               const float* __restrict__ ct_l, float* __restrict__ agg) {
  int e = blockIdx.x;
  int d = threadIdx.x;
  if (d >= D_DIM) return;
  int r = row[e], c = col[e], cc = ec[e];
  float v = h[(size_t)c * D_DIM + d] + ct_l[cc * D_DIM + d];
  atomicAdd(&agg[(size_t)r * D_DIM + d], v);
}

__global__ void bn_stats_kernel(const float* __restrict__ x, float* __restrict__ stats, int N) {
  int d = threadIdx.x;
  if (d >= D_DIM) return;
  float s = 0.f, s2 = 0.f;
  for (int n = blockIdx.x; n < N; n += gridDim.x) {
    float v = x[(size_t)n * D_DIM + d];
    s += v;
    s2 += v * v;
  }
  atomicAdd(&stats[d], s);
  atomicAdd(&stats[D_DIM + d], s2);
}

__global__ void bn_final_kernel(const float* __restrict__ stats, const float* __restrict__ gamma_l,
                                const float* __restrict__ beta_l, float* __restrict__ bnsc,
                                float* __restrict__ bnsh, int N) {
  int d = threadIdx.x;
  if (d >= D_DIM) return;
  float inv_n = 1.0f / (float)N;
  float mean = stats[d] * inv_n;
  float var = stats[D_DIM + d] * inv_n - mean * mean;
  float inv = rsqrtf(var + 1e-5f);
  float sc = gamma_l[d] * inv;
  bnsc[d] = sc;
  bnsh[d] = beta_l[d] - mean * sc;
}

template <bool RELU>
__global__ void bn_apply_kernel(float* __restrict__ x, const float* __restrict__ bnsc,
                                const float* __restrict__ bnsh) {
  int n = blockIdx.x;
  int d = threadIdx.x;
  if (d >= D_DIM) return;
  size_t i = (size_t)n * D_DIM + d;
  float v = x[i] * bnsc[d] + bnsh[d];
  if (RELU) v = fmaxf(v, 0.f);
  x[i] = v;
}

__global__ void pool_scatter_kernel(const float* __restrict__ h, const int* __restrict__ batch,
                                    float* __restrict__ pool, int* __restrict__ pcnt) {
  int n = blockIdx.x;
  int d = threadIdx.x;
  if (d >= D_DIM) return;
  int g = batch[n];
  atomicAdd(&pool[(size_t)g * D_DIM + d], h[(size_t)n * D_DIM + d]);
  if (d == 0) atomicAdd(&pcnt[g], 1);
}

__global__ void pool_div_kernel(float* __restrict__ pool, const int* __restrict__ pcnt) {
  int g = blockIdx.x;
  int d = threadIdx.x;
  if (d >= D_DIM) return;
  float c = (float)pcnt[g];
  if (c < 1.f) c = 1.f;
  pool[(size_t)g * D_DIM + d] /= c;
}

// ---------------- GEMM: C[M,N] = act(A[M,K] @ B[K,N] + bias) ----------------
// BM=128, BN=64, BK=16; 256 threads; per-thread 8x4 micro-tile (VALU fp32).

template <typename AT, bool RELU, typename OT>
__global__ __launch_bounds__(256) void gemm_kernel(const AT* __restrict__ A,
                                                   const float* __restrict__ B,
                                                   const float* __restrict__ bias,
                                                   OT* __restrict__ C, int M, int N, int K) {
  constexpr int BM = 128, BN = 64, BK = 16;
  __shared__ float As[BK][BM + 8];
  __shared__ float Bs[BK][BN];

  int m0 = blockIdx.x * BM;
  int n0 = blockIdx.y * BN;
  int tid = threadIdx.x;

  int trow = tid >> 4;  // 0..15 -> rows trow*8..+7
  int tcol = tid & 15;  // 0..15 -> cols tcol*4..+3

  int lr = tid >> 1;        // 0..127: A row within tile
  int lh = (tid & 1) * 8;   // k offset 0 or 8
  int bkr = tid >> 4;       // 0..15: B k-row
  int bc = (tid & 15) * 4;  // 0..60: B col

  float acc[8][4] = {};

  int nk = (K + BK - 1) / BK;
  for (int kt = 0; kt < nk; ++kt) {
    int k0 = kt * BK;
    // ---- load A tile (transposed into As[k][m]) ----
    {
      float v[8];
      int gr = m0 + lr;
      int kbase = k0 + lh;
      if (gr < M && (K - kbase) >= 8) {
        if constexpr (std::is_same<AT, float>::value) {
          const float* ap = A + (size_t)gr * K + kbase;
          float4 x0 = *(const float4*)(ap);
          float4 x1 = *(const float4*)(ap + 4);
          v[0] = x0.x; v[1] = x0.y; v[2] = x0.z; v[3] = x0.w;
          v[4] = x1.x; v[5] = x1.y; v[6] = x1.z; v[7] = x1.w;
        } else {
          const bf16* ap = (const bf16*)A + (size_t)gr * K + kbase;
          uint4 raw = *(const uint4*)(ap);
          v[0] = bf_raw2f(raw.x & 0xffffu); v[1] = bf_raw2f(raw.x >> 16);
          v[2] = bf_raw2f(raw.y & 0xffffu); v[3] = bf_raw2f(raw.y >> 16);
          v[4] = bf_raw2f(raw.z & 0xffffu); v[5] = bf_raw2f(raw.z >> 16);
          v[6] = bf_raw2f(raw.w & 0xffffu); v[7] = bf_raw2f(raw.w >> 16);
        }
      } else {
#pragma unroll
        for (int j = 0; j < 8; ++j) {
          int k = kbase + j;
          if (gr < M && k < K) {
            if constexpr (std::is_same<AT, float>::value)
              v[j] = A[(size_t)gr * K + k];
            else
              v[j] = __bfloat162float(((const bf16*)A)[(size_t)gr * K + k]);
          } else {
            v[j] = 0.f;
          }
        }
      }
#pragma unroll
      for (int j = 0; j < 8; ++j) As[lh + j][lr] = v[j];
    }
    // ---- load B tile ----
    {
      int gk = k0 + bkr;
      float4 bv = {0.f, 0.f, 0.f, 0.f};
      if (gk < K) {
        int gc = n0 + bc;
        if (gc + 3 < N) {
          bv = *(const float4*)(B + (size_t)gk * N + gc);
        } else {
          float tmp[4];
#pragma unroll
          for (int j = 0; j < 4; ++j) tmp[j] = (gc + j < N) ? B[(size_t)gk * N + gc + j] : 0.f;
          bv.x = tmp[0]; bv.y = tmp[1]; bv.z = tmp[2]; bv.w = tmp[3];
        }
      }
      *(float4*)&Bs[bkr][bc] = bv;
    }
    __syncthreads();
    // ---- compute ----
#pragma unroll
    for (int kk = 0; kk < BK; ++kk) {
      float4 a0 = *(const float4*)&As[kk][trow * 8];
      float4 a1 = *(const float4*)&As[kk][trow * 8 + 4];
      float4 b = *(const float4*)&Bs[kk][tcol * 4];
      float av[8] = {a0.x, a0.y, a0.z, a0.w, a1.x, a1.y, a1.z, a1.w};
      float bv[4] = {b.x, b.y, b.z, b.w};
#pragma unroll
      for (int i = 0; i < 8; ++i)
#pragma unroll
        for (int j = 0; j < 4; ++j) acc[i][j] += av[i] * bv[j];
    }
    __syncthreads();
  }

  // ---- epilogue ----
#pragma unroll
  for (int i = 0; i < 8; ++i) {
    int r = m0 + trow * 8 + i;
    if (r >= M) break;
#pragma unroll
    for (int j = 0; j < 4; ++j) {
      int c = n0 + tcol * 4 + j;
      if (c < N) {
        float v = acc[i][j] + bias[c];
        if (RELU) v = fmaxf(v, 0.f);
        if constexpr (std::is_same<OT, float>::value)
          C[(size_t)r * N + c] = v;
        else
          C[(size_t)r * N + c] = __float2bfloat16(v);
      }
    }
  }
}

// ---------------- launch ----------------

extern "C" void kernel_launch(void* const* d_in, const int* in_sizes, int n_in,
                              void* d_out, int out_size, void* d_ws, size_t ws_size,
                              hipStream_t stream) {
  const int* atom = (const int*)d_in[0];
  const int* chir = (const int*)d_in[1];
  const int* eidx = (const int*)d_in[2];
  const int* btype = (const int*)d_in[3];
  const int* bdir = (const int*)d_in[4];
  const int* batch = (const int*)d_in[5];
  const float* x_emb1 = (const float*)d_in[6];
  const float* x_emb2 = (const float*)d_in[7];
  const float* ee1 = (const float*)d_in[8];
  const float* ee2 = (const float*)d_in[9];
  const float* W1 = (const float*)d_in[10];
  const float* b1 = (const float*)d_in[11];
  const float* W2 = (const float*)d_in[12];
  const float* b2 = (const float*)d_in[13];
  const float* gamma = (const float*)d_in[14];
  const float* beta = (const float*)d_in[15];
  const float* featW = (const float*)d_in[16];
  const float* featb = (const float*)d_in[17];
  const float* projW = (const float*)d_in[18];
  const float* projb = (const float*)d_in[19];

  const int N = in_sizes[0];
  const int E = in_sizes[2] / 2;
  const int PROJ = in_sizes[19];
  const int FEAT = in_sizes[17];
  const int G = out_size / PROJ;
  const int L = in_sizes[11] / (2 * D_DIM);
  const int D2 = 2 * D_DIM;

  const int* row = eidx;
  const int* col = eidx + E;

  // ---- workspace layout (ping-pong; total ~244 MB) ----
  char* ws = (char*)d_ws;
  size_t off = 0;
  auto alloc = [&](size_t bytes) -> char* {
    char* p = ws + off;
    off += (bytes + 255) & ~(size_t)255;
    return p;
  };
  float* B0 = (float*)alloc((size_t)N * D_DIM * 4);       // ping
  float* B1 = (float*)alloc((size_t)N * D_DIM * 4);       // pong
  float* CT = (float*)alloc((size_t)L * 13 * D_DIM * 4);  // combo edge-emb tables
  int* EC = (int*)alloc((size_t)E * 4);                   // per-edge combo index
  float* STATS = (float*)alloc(2 * D_DIM * 4);
  float* BNSC = (float*)alloc(D_DIM * 4);
  float* BNSH = (float*)alloc(D_DIM * 4);
  (void)ws_size;

  init_h_kernel<<<N, TPB, 0, stream>>>(atom, chir, x_emb1, x_emb2, B0);
  combo_kernel<<<L * 13, TPB, 0, stream>>>(ee1, ee2, CT);
  edge_combo_kernel<<<(E + 255) / 256, 256, 0, stream>>>(btype, bdir, EC, E);

  float* hbuf = B0;  // holds h at layer start
  float* tbuf = B1;  // scratch: agg, then h2

  for (int l = 0; l < L; ++l) {
    const float* ctl = CT + (size_t)l * 13 * D_DIM;
    // agg = h + self-loop-const, then scatter-add edge messages
    agg_init_kernel<<<N, TPB, 0, stream>>>(hbuf, ctl, tbuf);
    scatter_kernel<<<E, TPB, 0, stream>>>(hbuf, row, col, EC, ctl, tbuf);
    // hid = relu(agg @ W1 + b1) -> bf16, written INTO hbuf (h is dead now)
    {
      dim3 g((N + 127) / 128, (D2 + 63) / 64);
      gemm_kernel<float, true, bf16><<<g, 256, 0, stream>>>(
          tbuf, W1 + (size_t)l * D_DIM * D2, b1 + (size_t)l * D2, (bf16*)hbuf, N, D2, D_DIM);
    }
    // h2 = hid @ W2 + b2 -> fp32, written into tbuf (agg is dead now)
    {
      dim3 g((N + 127) / 128, (D_DIM + 63) / 64);
      gemm_kernel<bf16, false, float><<<g, 256, 0, stream>>>(
          (const bf16*)hbuf, W2 + (size_t)l * D2 * D_DIM, b2 + (size_t)l * D_DIM, tbuf, N, D_DIM,
          D2);
    }
    // BatchNorm (training-mode batch stats) + relu except last layer
    zero_u32_kernel<<<2, 320, 0, stream>>>((unsigned int*)STATS, 2 * D_DIM);
    bn_stats_kernel<<<512, TPB, 0, stream>>>(tbuf, STATS, N);
    bn_final_kernel<<<1, TPB, 0, stream>>>(STATS, gamma + (size_t)l * D_DIM,
                                           beta + (size_t)l * D_DIM, BNSC, BNSH, N);
    if (l < L - 1)
      bn_apply_kernel<true><<<N, TPB, 0, stream>>>(tbuf, BNSC, BNSH);
    else
      bn_apply_kernel<false><<<N, TPB, 0, stream>>>(tbuf, BNSC, BNSH);
    // swap: h now lives in tbuf
    float* tmp = hbuf;
    hbuf = tbuf;
    tbuf = tmp;
  }

  // final h is in hbuf; tbuf is free -> alias POOL/PCNT/FEATB into it
  float* POOL = tbuf;                       // [G, D]
  int* PCNT = (int*)(POOL + (size_t)G * D_DIM);  // [G]
  float* FEATB = (float*)(PCNT + G);        // [G, FEAT] (16B-aligned: G*301*4)

  {
    long long nz = (long long)G * D_DIM + G;
    int blocks = (int)((nz + 255) / 256);
    if (blocks > 2048) blocks = 2048;
    zero_u32_kernel<<<blocks, 256, 0, stream>>>((unsigned int*)POOL, nz);
  }
  pool_scatter_kernel<<<N, TPB, 0, stream>>>(hbuf, batch, POOL, PCNT);
  pool_div_kernel<<<G, TPB, 0, stream>>>(POOL, PCNT);

  {
    dim3 g((G + 127) / 128, (FEAT + 63) / 64);
    gemm_kernel<float, false, float><<<g, 256, 0, stream>>>(POOL, featW, featb, FEATB, G, FEAT,
                                                            D_DIM);
  }
  {
    dim3 g((G + 127) / 128, (PROJ + 63) / 64);
    gemm_kernel<float, false, float><<<g, 256, 0, stream>>>(FEATB, projW, projb, (float*)d_out, G,
                                                            PROJ, FEAT);
  }
}

// Round 3
// 4454.912 us; speedup vs baseline: 2.4204x; 2.4204x over previous
//
#include <hip/hip_runtime.h>
#include <hip/hip_bf16.h>

typedef __bf16 bf16_t;
typedef bf16_t bf16x8 __attribute__((ext_vector_type(8)));
typedef float f32x4 __attribute__((ext_vector_type(4)));

#define D_DIM 300
#define TPB 320

__device__ inline f32x4 mfma16(bf16x8 a, bf16x8 b, f32x4 c) {
  return __builtin_amdgcn_mfma_f32_16x16x32_bf16(a, b, c, 0, 0, 0);
}

__device__ inline void split2(float x, unsigned short& h, unsigned short& l) {
  bf16_t hb = (bf16_t)x;
  float hf = (float)hb;
  bf16_t lb = (bf16_t)(x - hf);
  h = __builtin_bit_cast(unsigned short, hb);
  l = __builtin_bit_cast(unsigned short, lb);
}

// ---------------- utility ----------------

__global__ void zero_u32_kernel(unsigned int* __restrict__ p, long long n) {
  long long i = (long long)blockIdx.x * blockDim.x + threadIdx.x;
  long long s = (long long)gridDim.x * blockDim.x;
  for (; i < n; i += s) p[i] = 0u;
}

// ---------------- graph prep ----------------

__global__ void init_h_kernel(const int* __restrict__ atom, const int* __restrict__ chir,
                              const float* __restrict__ e1, const float* __restrict__ e2,
                              float* __restrict__ h) {
  int n = blockIdx.x;
  int d = threadIdx.x;
  if (d >= D_DIM) return;
  int a = atom[n], c = chir[n];
  h[(size_t)n * D_DIM + d] = e1[a * D_DIM + d] + e2[c * D_DIM + d];
}

__global__ void combo_kernel(const float* __restrict__ ee1, const float* __restrict__ ee2,
                             float* __restrict__ ct) {
  int l = blockIdx.x / 13, c = blockIdx.x % 13;
  int d = threadIdx.x;
  if (d >= D_DIM) return;
  int bt = (c < 12) ? (c / 3) : 4;
  int bd = (c < 12) ? (c % 3) : 0;
  ct[((size_t)(l * 13 + c)) * D_DIM + d] =
      ee1[(size_t)(l * 5 + bt) * D_DIM + d] + ee2[(size_t)(l * 3 + bd) * D_DIM + d];
}

__global__ void edge_combo_kernel(const int* __restrict__ bt, const int* __restrict__ bd,
                                  int* __restrict__ ec, int E) {
  int e = blockIdx.x * blockDim.x + threadIdx.x;
  if (e < E) ec[e] = bt[e] * 3 + bd[e];
}

// ---------------- CSR build ----------------

__global__ void csr_count_kernel(const int* __restrict__ row, int* __restrict__ deg, int E) {
  int e = blockIdx.x * blockDim.x + threadIdx.x;
  if (e < E) atomicAdd(&deg[row[e]], 1);
}

#define SCAN_T 1024
__global__ void scan_kernel(const int* __restrict__ deg, int* __restrict__ off,
                            int* __restrict__ cur, int n) {
  __shared__ int buf[SCAN_T];
  __shared__ int carry;
  int t = threadIdx.x;
  if (t == 0) carry = 0;
  __syncthreads();
  for (int base = 0; base < n; base += SCAN_T) {
    int i = base + t;
    int v = (i < n) ? deg[i] : 0;
    buf[t] = v;
    __syncthreads();
#pragma unroll
    for (int s = 1; s < SCAN_T; s <<= 1) {
      int add = (t >= s) ? buf[t - s] : 0;
      __syncthreads();
      buf[t] += add;
      __syncthreads();
    }
    int exc = buf[t] - v + carry;
    if (i < n) {
      off[i] = exc;
      cur[i] = exc;
    }
    __syncthreads();
    if (t == SCAN_T - 1) carry += buf[SCAN_T - 1];
    __syncthreads();
  }
  if (t == 0) off[n] = carry;
}

__global__ void csr_fill_kernel(const int* __restrict__ row, const int* __restrict__ col,
                                const int* __restrict__ ec, int* __restrict__ cur,
                                int* __restrict__ scol, int* __restrict__ sec, int E) {
  int e = blockIdx.x * blockDim.x + threadIdx.x;
  if (e < E) {
    int r = row[e];
    int p = atomicAdd(&cur[r], 1);
    scol[p] = col[e];
    sec[p] = ec[e];
  }
}

// gather: one wave per node. acc = h[n] + selfconst + sum_edges (h[col] + ct[ec])
__global__ __launch_bounds__(256) void gather_kernel(
    const float* __restrict__ h, const int* __restrict__ off, const int* __restrict__ scol,
    const int* __restrict__ sec, const float* __restrict__ ct_l, float* __restrict__ agg, int N) {
  int wid = threadIdx.x >> 6;
  int lane = threadIdx.x & 63;
  int n = blockIdx.x * 4 + wid;
  if (n >= N) return;
  float acc[5];
#pragma unroll
  for (int c = 0; c < 5; ++c) {
    int d = c * 64 + lane;
    acc[c] = (d < D_DIM) ? h[(size_t)n * D_DIM + d] + ct_l[12 * D_DIM + d] : 0.f;
  }
  int p0 = off[n], p1 = off[n + 1];
  for (int p = p0; p < p1; ++p) {
    int sc = scol[p];
    int se = sec[p];
    const float* hp = h + (size_t)sc * D_DIM;
    const float* cp = ct_l + se * D_DIM;
#pragma unroll
    for (int c = 0; c < 5; ++c) {
      int d = c * 64 + lane;
      if (d < D_DIM) acc[c] += hp[d] + cp[d];
    }
  }
#pragma unroll
  for (int c = 0; c < 5; ++c) {
    int d = c * 64 + lane;
    if (d < D_DIM) agg[(size_t)n * D_DIM + d] = acc[c];
  }
}

// ---------------- BatchNorm ----------------

__global__ void bn_stats_kernel(const float* __restrict__ x, float* __restrict__ stats, int N) {
  int d = threadIdx.x;
  if (d >= D_DIM) return;
  float s = 0.f, s2 = 0.f;
  for (int n = blockIdx.x; n < N; n += gridDim.x) {
    float v = x[(size_t)n * D_DIM + d];
    s += v;
    s2 += v * v;
  }
  atomicAdd(&stats[d], s);
  atomicAdd(&stats[D_DIM + d], s2);
}

__global__ void bn_final_kernel(const float* __restrict__ stats, const float* __restrict__ gamma_l,
                                const float* __restrict__ beta_l, float* __restrict__ bnsc,
                                float* __restrict__ bnsh, int N) {
  int d = threadIdx.x;
  if (d >= D_DIM) return;
  float inv_n = 1.0f / (float)N;
  float mean = stats[d] * inv_n;
  float var = stats[D_DIM + d] * inv_n - mean * mean;
  float inv = rsqrtf(var + 1e-5f);
  float sc = gamma_l[d] * inv;
  bnsc[d] = sc;
  bnsh[d] = beta_l[d] - mean * sc;
}

template <bool RELU>
__global__ void bn_apply_kernel(float* __restrict__ x, const float* __restrict__ bnsc,
                                const float* __restrict__ bnsh) {
  int n = blockIdx.x;
  int d = threadIdx.x;
  if (d >= D_DIM) return;
  size_t i = (size_t)n * D_DIM + d;
  float v = x[i] * bnsc[d] + bnsh[d];
  if (RELU) v = fmaxf(v, 0.f);
  x[i] = v;
}

// ---------------- pooling ----------------

__global__ void pool_scatter_kernel(const float* __restrict__ h, const int* __restrict__ batch,
                                    float* __restrict__ pool, int* __restrict__ pcnt) {
  int n = blockIdx.x;
  int d = threadIdx.x;
  if (d >= D_DIM) return;
  int g = batch[n];
  atomicAdd(&pool[(size_t)g * D_DIM + d], h[(size_t)n * D_DIM + d]);
  if (d == 0) atomicAdd(&pcnt[g], 1);
}

__global__ void pool_div_kernel(float* __restrict__ pool, const int* __restrict__ pcnt) {
  int g = blockIdx.x;
  int d = threadIdx.x;
  if (d >= D_DIM) return;
  float c = (float)pcnt[g];
  if (c < 1.f) c = 1.f;
  pool[(size_t)g * D_DIM + d] /= c;
}

// ---------------- weight transpose + hi/lo split ----------------
// src: W [K][N] fp32 row-major  ->  Th/Tl [Npad][Kpad] bf16 (zero-padded)

__global__ void wtrans_kernel(const float* __restrict__ W, unsigned short* __restrict__ Th,
                              unsigned short* __restrict__ Tl, int K, int N, int Kpad, int Npad) {
  __shared__ float tile[32][65];
  int t = threadIdx.x;
  int k0 = blockIdx.y * 32, n0 = blockIdx.x * 64;
#pragma unroll
  for (int q = 0; q < 8; ++q) {
    int idx = t + q * 256;
    int r = idx >> 6, c = idx & 63;
    int gk = k0 + r, gn = n0 + c;
    tile[r][c] = (gk < K && gn < N) ? W[(size_t)gk * N + gn] : 0.f;
  }
  __syncthreads();
  int c = t >> 2;
  int rq = (t & 3) * 8;
  unsigned int ph[4], pl[4];
#pragma unroll
  for (int j = 0; j < 4; ++j) {
    unsigned short h0, l0, h1, l1;
    split2(tile[rq + 2 * j][c], h0, l0);
    split2(tile[rq + 2 * j + 1][c], h1, l1);
    ph[j] = (unsigned int)h0 | ((unsigned int)h1 << 16);
    pl[j] = (unsigned int)l0 | ((unsigned int)l1 << 16);
  }
  size_t off = (size_t)(n0 + c) * Kpad + k0 + rq;
  *(uint4*)(Th + off) = make_uint4(ph[0], ph[1], ph[2], ph[3]);
  *(uint4*)(Tl + off) = make_uint4(pl[0], pl[1], pl[2], pl[3]);
}

// ---------------- MFMA GEMM ----------------
// C[M,N] = act(A[M,K] @ B[K,N] + bias)
// BM=128, BN=64, BK=32; 256 threads (4 waves as 2x2); per wave 4x2 frags of 16x16.
// A_BF16=false: A fp32, split hi/lo in LDS, 3-term MFMA (~fp32 precision).
// A_BF16=true : A bf16 (already rounded), 2-term MFMA (B hi/lo exact).
// B pre-split, transposed [Npad][Kpad] bf16.

template <bool A_BF16, bool RELU, bool OUT_BF16>
__global__ __launch_bounds__(256) void mfma_gemm(const void* __restrict__ Aptr,
                                                 const unsigned short* __restrict__ Bh,
                                                 const unsigned short* __restrict__ Bl,
                                                 const float* __restrict__ bias,
                                                 void* __restrict__ Cptr, int M, int N, int K,
                                                 int astride, int kpad, int cstride) {
  __shared__ __align__(16) char ldsA[16384];  // Ah [0,8K), Al [8K,16K)

  int t = threadIdx.x;
  int n0 = blockIdx.x * 64;
  int m0 = blockIdx.y * 128;

  int wid = t >> 6, lane = t & 63;
  int wm = wid >> 1, wn = wid & 1;
  int lrow = lane & 15, lk = lane >> 4;

  // staging mapping: thread t -> row t>>1, k-half (t&1)*16
  int srow = t >> 1;
  int skh = (t & 1) * 16;
  int sbase = (srow << 6) + (skh << 1);
  int smsk = (srow & 7) << 4;
  int gr = m0 + srow;

  f32x4 acc[4][2] = {};

  int nkt = kpad / 32;
  for (int kt = 0; kt < nkt; ++kt) {
    int k0 = kt * 32;
    // B loads (global; L1/L2-hot weight slabs)
    bf16x8 bhf[2], blf[2];
#pragma unroll
    for (int j = 0; j < 2; ++j) {
      int colb = n0 + wn * 32 + j * 16 + lrow;
      size_t bo = (size_t)colb * kpad + k0 + lk * 8;
      bhf[j] = *(const bf16x8*)(const void*)(Bh + bo);
      blf[j] = *(const bf16x8*)(const void*)(Bl + bo);
    }
    // ---- stage A ----
    int kg = k0 + skh;
    if constexpr (!A_BF16) {
      const float* A = (const float*)Aptr;
      float va[16];
      if (gr < M && kg + 16 <= K) {
        const float* ap = A + (size_t)gr * astride + kg;
        float4 x0 = ((const float4*)ap)[0];
        float4 x1 = ((const float4*)ap)[1];
        float4 x2 = ((const float4*)ap)[2];
        float4 x3 = ((const float4*)ap)[3];
        va[0] = x0.x; va[1] = x0.y; va[2] = x0.z; va[3] = x0.w;
        va[4] = x1.x; va[5] = x1.y; va[6] = x1.z; va[7] = x1.w;
        va[8] = x2.x; va[9] = x2.y; va[10] = x2.z; va[11] = x2.w;
        va[12] = x3.x; va[13] = x3.y; va[14] = x3.z; va[15] = x3.w;
      } else {
#pragma unroll
        for (int j = 0; j < 16; ++j)
          va[j] = (gr < M && kg + j < K) ? A[(size_t)gr * astride + kg + j] : 0.f;
      }
      unsigned int ph[8], pl[8];
#pragma unroll
      for (int j = 0; j < 8; ++j) {
        unsigned short h0, l0, h1, l1;
        split2(va[2 * j], h0, l0);
        split2(va[2 * j + 1], h1, l1);
        ph[j] = (unsigned int)h0 | ((unsigned int)h1 << 16);
        pl[j] = (unsigned int)l0 | ((unsigned int)l1 << 16);
      }
      *(uint4*)(ldsA + ((sbase) ^ smsk)) = make_uint4(ph[0], ph[1], ph[2], ph[3]);
      *(uint4*)(ldsA + ((sbase + 16) ^ smsk)) = make_uint4(ph[4], ph[5], ph[6], ph[7]);
      *(uint4*)(ldsA + 8192 + ((sbase) ^ smsk)) = make_uint4(pl[0], pl[1], pl[2], pl[3]);
      *(uint4*)(ldsA + 8192 + ((sbase + 16) ^ smsk)) = make_uint4(pl[4], pl[5], pl[6], pl[7]);
    } else {
      const unsigned short* A = (const unsigned short*)Aptr;
      uint4 c0, c1;
      if (gr < M && kg + 16 <= K) {
        const uint4* src = (const uint4*)(A + (size_t)gr * astride + kg);
        c0 = src[0];
        c1 = src[1];
      } else {
        unsigned short tmp[16];
#pragma unroll
        for (int j = 0; j < 16; ++j)
          tmp[j] = (gr < M && kg + j < K) ? A[(size_t)gr * astride + kg + j] : (unsigned short)0;
        unsigned int pw[8];
#pragma unroll
        for (int j = 0; j < 8; ++j)
          pw[j] = (unsigned int)tmp[2 * j] | ((unsigned int)tmp[2 * j + 1] << 16);
        c0 = make_uint4(pw[0], pw[1], pw[2], pw[3]);
        c1 = make_uint4(pw[4], pw[5], pw[6], pw[7]);
      }
      *(uint4*)(ldsA + ((sbase) ^ smsk)) = c0;
      *(uint4*)(ldsA + ((sbase + 16) ^ smsk)) = c1;
    }
    __syncthreads();
    // ---- fragments + MFMA ----
#pragma unroll
    for (int i = 0; i < 4; ++i) {
      int arow = wm * 64 + i * 16 + lrow;
      int aoff = (arow * 64 + lk * 16) ^ ((arow & 7) << 4);
      bf16x8 ah = *(const bf16x8*)(const void*)(ldsA + aoff);
      if constexpr (!A_BF16) {
        bf16x8 al = *(const bf16x8*)(const void*)(ldsA + 8192 + aoff);
#pragma unroll
        for (int j = 0; j < 2; ++j) {
          acc[i][j] = mfma16(ah, bhf[j], acc[i][j]);
          acc[i][j] = mfma16(ah, blf[j], acc[i][j]);
          acc[i][j] = mfma16(al, bhf[j], acc[i][j]);
        }
      } else {
#pragma unroll
        for (int j = 0; j < 2; ++j) {
          acc[i][j] = mfma16(ah, bhf[j], acc[i][j]);
          acc[i][j] = mfma16(ah, blf[j], acc[i][j]);
        }
      }
    }
    __syncthreads();
  }

  // ---- epilogue ----
#pragma unroll
  for (int i = 0; i < 4; ++i) {
#pragma unroll
    for (int j = 0; j < 2; ++j) {
      int gcol = n0 + wn * 32 + j * 16 + lrow;
      if (gcol >= N) continue;
      float bsv = bias[gcol];
#pragma unroll
      for (int r = 0; r < 4; ++r) {
        int grow = m0 + wm * 64 + i * 16 + lk * 4 + r;
        if (grow < M) {
          float v = acc[i][j][r] + bsv;
          if (RELU) v = fmaxf(v, 0.f);
          if constexpr (OUT_BF16)
            ((bf16_t*)Cptr)[(size_t)grow * cstride + gcol] = (bf16_t)v;
          else
            ((float*)Cptr)[(size_t)grow * cstride + gcol] = v;
        }
      }
    }
  }
}

// ---------------- launch ----------------

extern "C" void kernel_launch(void* const* d_in, const int* in_sizes, int n_in,
                              void* d_out, int out_size, void* d_ws, size_t ws_size,
                              hipStream_t stream) {
  const int* atom = (const int*)d_in[0];
  const int* chir = (const int*)d_in[1];
  const int* eidx = (const int*)d_in[2];
  const int* btype = (const int*)d_in[3];
  const int* bdir = (const int*)d_in[4];
  const int* batch = (const int*)d_in[5];
  const float* x_emb1 = (const float*)d_in[6];
  const float* x_emb2 = (const float*)d_in[7];
  const float* ee1 = (const float*)d_in[8];
  const float* ee2 = (const float*)d_in[9];
  const float* W1 = (const float*)d_in[10];
  const float* b1 = (const float*)d_in[11];
  const float* W2 = (const float*)d_in[12];
  const float* b2 = (const float*)d_in[13];
  const float* gamma = (const float*)d_in[14];
  const float* beta = (const float*)d_in[15];
  const float* featW = (const float*)d_in[16];
  const float* featb = (const float*)d_in[17];
  const float* projW = (const float*)d_in[18];
  const float* projb = (const float*)d_in[19];

  const int N = in_sizes[0];
  const int E = in_sizes[2] / 2;
  const int PROJ = in_sizes[19];
  const int FEAT = in_sizes[17];
  const int G = out_size / PROJ;
  const int L = in_sizes[11] / (2 * D_DIM);
  const int D2 = 2 * D_DIM;  // 600

  const int* row = eidx;
  const int* col = eidx + E;

  // padded K sizes
  const int KP1 = 320;  // ceil(300/32)*32
  const int KP2 = 608;  // ceil(600/32)*32
  const int KPF = 320;
  const int KPP = 512;
  const int NP1 = 640;  // ceil(600/64)*64
  const int NP2 = 320;  // ceil(300/64)*64
  const int NPF = 512;
  const int NPP = 256;

  // ---- workspace ----
  char* ws = (char*)d_ws;
  size_t off = 0;
  auto alloc = [&](size_t bytes) -> char* {
    char* p = ws + off;
    off += (bytes + 255) & ~(size_t)255;
    return p;
  };
  // two big ping-pong buffers: fp32 [N][300] (1200 B/row) == bf16 [N][600]
  float* B0 = (float*)alloc((size_t)N * D_DIM * 4);
  float* B1 = (float*)alloc((size_t)N * D_DIM * 4);
  float* CT = (float*)alloc((size_t)L * 13 * D_DIM * 4);
  int* EC = (int*)alloc((size_t)E * 4);
  int* DEG = (int*)alloc((size_t)N * 4);
  int* OFF = (int*)alloc((size_t)(N + 1) * 4);
  int* CUR = (int*)alloc((size_t)N * 4);
  int* SCOL = (int*)alloc((size_t)E * 4);
  int* SEC = (int*)alloc((size_t)E * 4);
  float* STATS = (float*)alloc(2 * D_DIM * 4);
  float* BNSC = (float*)alloc(D_DIM * 4);
  float* BNSH = (float*)alloc(D_DIM * 4);
  unsigned short* W1Th = (unsigned short*)alloc((size_t)L * NP1 * KP1 * 2);
  unsigned short* W1Tl = (unsigned short*)alloc((size_t)L * NP1 * KP1 * 2);
  unsigned short* W2Th = (unsigned short*)alloc((size_t)L * NP2 * KP2 * 2);
  unsigned short* W2Tl = (unsigned short*)alloc((size_t)L * NP2 * KP2 * 2);
  unsigned short* FTh = (unsigned short*)alloc((size_t)NPF * KPF * 2);
  unsigned short* FTl = (unsigned short*)alloc((size_t)NPF * KPF * 2);
  unsigned short* PTh = (unsigned short*)alloc((size_t)NPP * KPP * 2);
  unsigned short* PTl = (unsigned short*)alloc((size_t)NPP * KPP * 2);
  (void)ws_size;

  // ---- prep: embeddings, combos, CSR, weight tables ----
  init_h_kernel<<<N, TPB, 0, stream>>>(atom, chir, x_emb1, x_emb2, B0);
  combo_kernel<<<L * 13, TPB, 0, stream>>>(ee1, ee2, CT);
  edge_combo_kernel<<<(E + 255) / 256, 256, 0, stream>>>(btype, bdir, EC, E);

  zero_u32_kernel<<<(N + 255) / 256, 256, 0, stream>>>((unsigned int*)DEG, N);
  csr_count_kernel<<<(E + 255) / 256, 256, 0, stream>>>(row, DEG, E);
  scan_kernel<<<1, SCAN_T, 0, stream>>>(DEG, OFF, CUR, N);
  csr_fill_kernel<<<(E + 255) / 256, 256, 0, stream>>>(row, col, EC, CUR, SCOL, SEC, E);

  for (int l = 0; l < L; ++l) {
    wtrans_kernel<<<dim3(NP1 / 64, KP1 / 32), 256, 0, stream>>>(
        W1 + (size_t)l * D_DIM * D2, W1Th + (size_t)l * NP1 * KP1, W1Tl + (size_t)l * NP1 * KP1,
        D_DIM, D2, KP1, NP1);
    wtrans_kernel<<<dim3(NP2 / 64, KP2 / 32), 256, 0, stream>>>(
        W2 + (size_t)l * D2 * D_DIM, W2Th + (size_t)l * NP2 * KP2, W2Tl + (size_t)l * NP2 * KP2,
        D2, D_DIM, KP2, NP2);
  }
  wtrans_kernel<<<dim3(NPF / 64, KPF / 32), 256, 0, stream>>>(featW, FTh, FTl, D_DIM, FEAT, KPF,
                                                              NPF);
  wtrans_kernel<<<dim3(NPP / 64, KPP / 32), 256, 0, stream>>>(projW, PTh, PTl, FEAT, PROJ, KPP,
                                                              NPP);

  float* hbuf = B0;
  float* sbuf = B1;
  int gmy = (N + 127) / 128;

  for (int l = 0; l < L; ++l) {
    const float* ctl = CT + (size_t)l * 13 * D_DIM;
    // agg (sbuf) = h + selfconst + sum_nbr(h[col] + ee)
    gather_kernel<<<(N + 3) / 4, 256, 0, stream>>>(hbuf, OFF, SCOL, SEC, ctl, sbuf, N);
    // hid = relu(agg @ W1 + b1) -> bf16 [N][600] into hbuf (h dead)
    mfma_gemm<false, true, true><<<dim3(D2 / 64 + (D2 % 64 ? 1 : 0), gmy), 256, 0, stream>>>(
        sbuf, W1Th + (size_t)l * NP1 * KP1, W1Tl + (size_t)l * NP1 * KP1, b1 + (size_t)l * D2,
        hbuf, N, D2, D_DIM, D_DIM, KP1, D2);
    // h2 = hid @ W2 + b2 -> fp32 [N][300] into sbuf (agg dead)
    mfma_gemm<true, false, false><<<dim3((D_DIM + 63) / 64, gmy), 256, 0, stream>>>(
        hbuf, W2Th + (size_t)l * NP2 * KP2, W2Tl + (size_t)l * NP2 * KP2, b2 + (size_t)l * D_DIM,
        sbuf, N, D_DIM, D2, D2, KP2, D_DIM);
    // BatchNorm (+ relu except last)
    zero_u32_kernel<<<2, 320, 0, stream>>>((unsigned int*)STATS, 2 * D_DIM);
    bn_stats_kernel<<<512, TPB, 0, stream>>>(sbuf, STATS, N);
    bn_final_kernel<<<1, TPB, 0, stream>>>(STATS, gamma + (size_t)l * D_DIM,
                                           beta + (size_t)l * D_DIM, BNSC, BNSH, N);
    if (l < L - 1)
      bn_apply_kernel<true><<<N, TPB, 0, stream>>>(sbuf, BNSC, BNSH);
    else
      bn_apply_kernel<false><<<N, TPB, 0, stream>>>(sbuf, BNSC, BNSH);
    float* tmp = hbuf;
    hbuf = sbuf;
    sbuf = tmp;
  }

  // final h in hbuf; sbuf free -> POOL/PCNT/FEATB
  float* POOL = sbuf;
  int* PCNT = (int*)(POOL + (size_t)G * D_DIM);
  float* FEATB = (float*)(PCNT + G);

  {
    long long nz = (long long)G * D_DIM + G;
    int blocks = (int)((nz + 255) / 256);
    if (blocks > 2048) blocks = 2048;
    zero_u32_kernel<<<blocks, 256, 0, stream>>>((unsigned int*)POOL, nz);
  }
  pool_scatter_kernel<<<N, TPB, 0, stream>>>(hbuf, batch, POOL, PCNT);
  pool_div_kernel<<<G, TPB, 0, stream>>>(POOL, PCNT);

  mfma_gemm<false, false, false><<<dim3(NPF / 64, (G + 127) / 128), 256, 0, stream>>>(
      POOL, FTh, FTl, featb, FEATB, G, FEAT, D_DIM, D_DIM, KPF, FEAT);
  mfma_gemm<false, false, false><<<dim3(NPP / 64, (G + 127) / 128), 256, 0, stream>>>(
      FEATB, PTh, PTl, projb, d_out, G, PROJ, FEAT, FEAT, KPP, PROJ);
}